// Round 7
// baseline (610.633 us; speedup 1.0000x reference)
//
#include <hip/hip_runtime.h>
#include <hip/hip_bf16.h>
#include <stdint.h>

// ---------------------------------------------------------------------------
// Round 7: R6 with the scratch-spill pathology fixed.
//  Root cause of R4/R5/R6's ~900MB FETCH / ~250-460MB WRITE: gathered qc/cc
//  values held in address-taken locals (pointer arrays / &array[r]) -> SROA
//  defeated -> per-tile scratch spill/fill (rule #20). Fix: acc-init uses
//  ONLY named uint4s via .x/.y/.z/.w member access (macro-expanded, static).
//  Everything else identical to R6: 768thr/(768,3), permuted qc/cc rows,
//  2-deep pipelined register gather, CSR sort, segmented-reduce scatter.
// ---------------------------------------------------------------------------

typedef __bf16 bfx8 __attribute__((ext_vector_type(8)));
typedef float f32x4 __attribute__((ext_vector_type(4)));
typedef short s16x2 __attribute__((ext_vector_type(2)));

__device__ __forceinline__ unsigned short bfbits(float f) {
  __bf16 b = (__bf16)f;
  return __builtin_bit_cast(unsigned short, b);
}
__device__ __forceinline__ float bfu2f(unsigned short u) {
  return __builtin_bit_cast(float, ((unsigned)u) << 16);
}
__device__ __forceinline__ unsigned pkpair(float a, float b) {
  return (unsigned)bfbits(a) | ((unsigned)bfbits(b) << 16);
}
__device__ __forceinline__ unsigned pk2(unsigned x, unsigned y) {
  float lo = bfu2f((unsigned short)(x & 0xffffu)) + bfu2f((unsigned short)(y & 0xffffu));
  float hi = bfu2f((unsigned short)(x >> 16)) + bfu2f((unsigned short)(y >> 16));
  return pkpair(lo, hi);
}

__device__ __forceinline__ void atomAddBf2(unsigned short* p, unsigned v) {
#if defined(__has_builtin) && __has_builtin(__builtin_amdgcn_global_atomic_fadd_v2bf16)
  __builtin_amdgcn_global_atomic_fadd_v2bf16(
      (__attribute__((address_space(1))) s16x2*)p, __builtin_bit_cast(s16x2, v));
#else
  unsigned* q = (unsigned*)p;
  unsigned old = *q;
  while (true) {
    unsigned nv = pk2(old, v);
    unsigned prev = atomicCAS(q, old, nv);
    if (prev == old) break;
    old = prev;
  }
#endif
}

// swizzled byte offset of element (row, kbyte) in a [rows][128] bf16 LDS tile
__device__ __forceinline__ int swzb(int row, int kbyte) {
  return (row * 256 + kbyte) ^ ((row & 7) << 4);
}

// linear copy of one pre-swizzled transposed weight (32768 B) into LDS
__device__ __forceinline__ void stage_w(const unsigned short* wsrc, char* dst, int tid, int nth) {
  const uint4* s = (const uint4*)wsrc;
  uint4* d = (uint4*)dst;
  for (int i = tid; i < 2048; i += nth) d[i] = s[i];
}

// wave GEMM: [16 rows x 128] @ [128 x 128] -> acc[8] tiles (16x16), accumulate
template <bool A_FROM_LDS>
__device__ __forceinline__ void wave_gemm(const char* WtL, const char* XL,
                                          const bfx8* aF, f32x4 acc[8],
                                          int lg, int lr) {
#pragma unroll
  for (int ks = 0; ks < 4; ++ks) {
    bfx8 a;
    if (A_FROM_LDS)
      a = *(const bfx8*)(XL + swzb(lr, (ks * 32 + lg * 8) * 2));
    else
      a = aF[ks];
#pragma unroll
    for (int t = 0; t < 8; ++t) {
      int n = t * 16 + lr;
      bfx8 b = *(const bfx8*)(WtL + swzb(n, (ks * 32 + lg * 8) * 2));
      acc[t] = __builtin_amdgcn_mfma_f32_16x16x32_bf16(a, b, acc[t], 0, 0, 0);
    }
  }
}

// in-register GroupNorm(1 group over 128 ch); gamma/beta loaded per call (L1)
__device__ __forceinline__ void wave_gn(f32x4 acc[8], const float* __restrict__ g,
                                        const float* __restrict__ b, int lr, bool do_relu) {
  float s0 = 0.f, s1 = 0.f, s2 = 0.f, s3 = 0.f;
  float q0 = 0.f, q1 = 0.f, q2 = 0.f, q3 = 0.f;
#pragma unroll
  for (int t = 0; t < 8; ++t) {
    float v0 = acc[t][0], v1 = acc[t][1], v2 = acc[t][2], v3 = acc[t][3];
    s0 += v0; q0 += v0 * v0;
    s1 += v1; q1 += v1 * v1;
    s2 += v2; q2 += v2 * v2;
    s3 += v3; q3 += v3 * v3;
  }
#pragma unroll
  for (int m = 1; m <= 8; m <<= 1) {
    s0 += __shfl_xor(s0, m, 64); q0 += __shfl_xor(q0, m, 64);
    s1 += __shfl_xor(s1, m, 64); q1 += __shfl_xor(q1, m, 64);
    s2 += __shfl_xor(s2, m, 64); q2 += __shfl_xor(q2, m, 64);
    s3 += __shfl_xor(s3, m, 64); q3 += __shfl_xor(q3, m, 64);
  }
  float mean[4], rstd[4];
  {
    const float inv = 1.f / 128.f;
    float m0 = s0 * inv, m1 = s1 * inv, m2 = s2 * inv, m3 = s3 * inv;
    mean[0] = m0; mean[1] = m1; mean[2] = m2; mean[3] = m3;
    rstd[0] = rsqrtf(q0 * inv - m0 * m0 + 1e-5f);
    rstd[1] = rsqrtf(q1 * inv - m1 * m1 + 1e-5f);
    rstd[2] = rsqrtf(q2 * inv - m2 * m2 + 1e-5f);
    rstd[3] = rsqrtf(q3 * inv - m3 * m3 + 1e-5f);
  }
#pragma unroll
  for (int t = 0; t < 8; ++t) {
    float gc = g[t * 16 + lr], bc = b[t * 16 + lr];
#pragma unroll
    for (int r = 0; r < 4; ++r) {
      float v = (acc[t][r] - mean[r]) * rstd[r] * gc + bc;
      if (do_relu) v = fmaxf(v, 0.f);
      acc[t][r] = v;
    }
  }
}

// write post-GN tile (C-layout) into wave-private swizzled LDS stage as bf16
__device__ __forceinline__ void wave_stage(char* XL, const f32x4 acc[8], int lg, int lr) {
#pragma unroll
  for (int t = 0; t < 8; ++t) {
#pragma unroll
    for (int r = 0; r < 4; ++r) {
      int row = 4 * lg + r, c = t * 16 + lr;
      *(__bf16*)(XL + swzb(row, 2 * c)) = (__bf16)acc[t][r];
    }
  }
}

// pack 8 acc t-values of row r into a uint4 (for permuted qc/cc stores)
__device__ __forceinline__ uint4 pack_row(const f32x4 acc[8], int r) {
  uint4 o;
  o.x = pkpair(acc[0][r], acc[1][r]);
  o.y = pkpair(acc[2][r], acc[3][r]);
  o.z = pkpair(acc[4][r], acc[5][r]);
  o.w = pkpair(acc[6][r], acc[7][r]);
  return o;
}

// fully-static acc-init from named uint4s: NO address-taking, NO arrays.
// position p=8*lr+t holds channel n=16*t+lr; word t>>1, half t&1.
#define ACC_INIT_ROW(R, QV, CV)                                                            \
  acc[0][R] = bfu2f((unsigned short)((QV).x & 0xffffu)) +                                  \
              bfu2f((unsigned short)((CV).x & 0xffffu));                                   \
  acc[1][R] = bfu2f((unsigned short)((QV).x >> 16)) +                                      \
              bfu2f((unsigned short)((CV).x >> 16));                                       \
  acc[2][R] = bfu2f((unsigned short)((QV).y & 0xffffu)) +                                  \
              bfu2f((unsigned short)((CV).y & 0xffffu));                                   \
  acc[3][R] = bfu2f((unsigned short)((QV).y >> 16)) +                                      \
              bfu2f((unsigned short)((CV).y >> 16));                                       \
  acc[4][R] = bfu2f((unsigned short)((QV).z & 0xffffu)) +                                  \
              bfu2f((unsigned short)((CV).z & 0xffffu));                                   \
  acc[5][R] = bfu2f((unsigned short)((QV).z >> 16)) +                                      \
              bfu2f((unsigned short)((CV).z >> 16));                                       \
  acc[6][R] = bfu2f((unsigned short)((QV).w & 0xffffu)) +                                  \
              bfu2f((unsigned short)((CV).w & 0xffffu));                                   \
  acc[7][R] = bfu2f((unsigned short)((QV).w >> 16)) +                                      \
              bfu2f((unsigned short)((CV).w >> 16));

// ---------------------------------------------------------------------------
// prep: transpose + bf16-convert + pre-swizzle the 8 [128x128] weights
// order: 0 W_d2, 1 W_c1_top, 2 W_c1_mid, 3 W_c1_bot, 4 W_c2, 5 W_q, 6 W_a, 7 W_l
// ---------------------------------------------------------------------------
__global__ void k_prep_weights(const float* Wd2, const float* Wc1, const float* Wc2,
                               const float* Wq, const float* Wa, const float* Wl,
                               unsigned short* wsW) {
  __shared__ unsigned short tmp[128 * 128];
  int m = blockIdx.x;
  const float* src;
  switch (m) {
    case 0: src = Wd2; break;
    case 1: src = Wc1; break;
    case 2: src = Wc1 + 128 * 128; break;
    case 3: src = Wc1 + 256 * 128; break;
    case 4: src = Wc2; break;
    case 5: src = Wq; break;
    case 6: src = Wa; break;
    default: src = Wl; break;
  }
  int tid = threadIdx.x;
#pragma unroll
  for (int i = 0; i < 16; ++i) {
    int lin = i * 256 + tid;
    float4 v = ((const float4*)src)[lin];
    ushort4 b;
    b.x = bfbits(v.x); b.y = bfbits(v.y); b.z = bfbits(v.z); b.w = bfbits(v.w);
    *(ushort4*)&tmp[lin * 4] = b;
  }
  __syncthreads();
  unsigned short* dst = wsW + (size_t)m * 16384;
#pragma unroll
  for (int i = 0; i < 16; ++i) {
    int lin = i * 256 + tid;
    int n = lin >> 5, q = lin & 31, k0 = q * 4;
    ushort4 b;
    b.x = tmp[(k0 + 0) * 128 + n];
    b.y = tmp[(k0 + 1) * 128 + n];
    b.z = tmp[(k0 + 2) * 128 + n];
    b.w = tmp[(k0 + 3) * 128 + n];
    *(ushort4*)((char*)dst + swzb(n, k0 * 2)) = b;
  }
}

// ---------------------------------------------------------------------------
// CSR build: rank-hist -> hierarchical scan -> fill (no atomics in fill)
// ---------------------------------------------------------------------------
__global__ void k_hist(const int* __restrict__ hi, int* cnt, int* rank, int E) {
  int e = blockIdx.x * 256 + threadIdx.x;
  if (e < E) rank[e] = atomicAdd(&cnt[hi[e]], 1);
}

__global__ void k_scan1(const int* __restrict__ cnt, int* bsum, int N) {
  __shared__ int red[256];
  int b = blockIdx.x, t = threadIdx.x;
  int i0 = b * 1024 + t * 4;
  int s = 0;
#pragma unroll
  for (int j = 0; j < 4; ++j) { int i = i0 + j; if (i < N) s += cnt[i]; }
  red[t] = s;
  __syncthreads();
  for (int d = 128; d > 0; d >>= 1) {
    if (t < d) red[t] += red[t + d];
    __syncthreads();
  }
  if (t == 0) bsum[b] = red[0];
}

__global__ __launch_bounds__(1024) void k_scan2(int* bsum, int nb) {
  __shared__ int sh[1024];
  int t = threadIdx.x;
  sh[t] = (t < nb) ? bsum[t] : 0;
  __syncthreads();
  for (int d = 1; d < 1024; d <<= 1) {
    int v = (t >= d) ? sh[t - d] : 0;
    __syncthreads();
    sh[t] += v;
    __syncthreads();
  }
  if (t < nb) bsum[t] = (t == 0) ? 0 : sh[t - 1];
}

__global__ void k_scan3(const int* __restrict__ cnt, const int* __restrict__ bsum,
                        int* base, int N) {
  __shared__ int tsum[256];
  int b = blockIdx.x, t = threadIdx.x;
  int i0 = b * 1024 + t * 4;
  int v[4]; int s = 0;
#pragma unroll
  for (int j = 0; j < 4; ++j) { int i = i0 + j; v[j] = (i < N) ? cnt[i] : 0; s += v[j]; }
  tsum[t] = s;
  __syncthreads();
  for (int d = 1; d < 256; d <<= 1) {
    int x = (t >= d) ? tsum[t - d] : 0;
    __syncthreads();
    tsum[t] += x;
    __syncthreads();
  }
  int off = bsum[b] + ((t == 0) ? 0 : tsum[t - 1]);
#pragma unroll
  for (int j = 0; j < 4; ++j) {
    int i = i0 + j;
    if (i < N) { base[i] = off; off += v[j]; }
  }
}

__global__ void k_fill(const int* __restrict__ hi, const int* __restrict__ wi,
                       const int* __restrict__ base, const int* __restrict__ rank,
                       uint2* hw, int E) {
  int e = blockIdx.x * 256 + threadIdx.x;
  if (e < E) {
    int h = hi[e];
    int p = base[h] + rank[e];
    hw[p] = make_uint2((unsigned)h, (unsigned)wi[e]);
  }
}

// ---------------------------------------------------------------------------
// ctx precompute: CC = ctx @ W_c1_bot, stored PERMUTED (row pos 8*lr+t)
// ---------------------------------------------------------------------------
__global__ __launch_bounds__(768, 3) void k_ctx(const float* __restrict__ ctx,
                                                const unsigned short* __restrict__ wsW,
                                                unsigned short* __restrict__ cc, int M) {
  __shared__ __align__(16) char lds[32768];
  int tid = threadIdx.x, wid = tid >> 6, lane = tid & 63, lg = lane >> 4, lr = lane & 15;
  stage_w(wsW + 3 * 16384, lds, tid, 768);
  __syncthreads();
  int nTiles = (M + 15) >> 4;
  int stride = gridDim.x * 12;
  for (int tile = blockIdx.x * 12 + wid; tile < nTiles; tile += stride) {
    int base = tile << 4;
    int row = base + lr; if (row >= M) row = M - 1;
    bfx8 cf[4];
#pragma unroll
    for (int ks = 0; ks < 4; ++ks) {
      int k0 = ks * 32 + lg * 8;
      const float4* p = (const float4*)&ctx[(size_t)row * 128 + k0];
      float4 a = p[0], b = p[1];
      bfx8 f;
      f[0] = (__bf16)a.x; f[1] = (__bf16)a.y; f[2] = (__bf16)a.z; f[3] = (__bf16)a.w;
      f[4] = (__bf16)b.x; f[5] = (__bf16)b.y; f[6] = (__bf16)b.z; f[7] = (__bf16)b.w;
      cf[ks] = f;
    }
    f32x4 acc[8];
#pragma unroll
    for (int t = 0; t < 8; ++t) acc[t] = 0.f;
    wave_gemm<false>(lds, nullptr, cf, acc, lg, lr);
#pragma unroll
    for (int r = 0; r < 4; ++r) {
      int grow = base + 4 * lg + r;
      if (grow < M)
        *(uint4*)(cc + (size_t)grow * 128 + 8 * lr) = pack_row(acc, r);
    }
  }
}

// ---------------------------------------------------------------------------
// agent precompute: QC = relu(gn(agts@W_q))@W_c1_mid, stored PERMUTED
// ---------------------------------------------------------------------------
__global__ __launch_bounds__(768, 3) void k_agents(const float* __restrict__ agts,
                                                   const float* __restrict__ g_q,
                                                   const float* __restrict__ b_q,
                                                   const unsigned short* __restrict__ wsW,
                                                   unsigned short* __restrict__ qc, int N) {
  __shared__ __align__(16) char lds[114688];
  char* WqL = lds;
  char* WcL = lds + 32768;
  int tid = threadIdx.x, wid = tid >> 6, lane = tid & 63, lg = lane >> 4, lr = lane & 15;
  char* actL = lds + 65536 + wid * 4096;
  stage_w(wsW + 5 * 16384, WqL, tid, 768);
  stage_w(wsW + 2 * 16384, WcL, tid, 768);
  __syncthreads();
  int nTiles = (N + 15) >> 4;
  int stride = gridDim.x * 12;
  for (int tile = blockIdx.x * 12 + wid; tile < nTiles; tile += stride) {
    int base = tile << 4;
    int row = base + lr; if (row >= N) row = N - 1;
    bfx8 af[4];
#pragma unroll
    for (int ks = 0; ks < 4; ++ks) {
      int k0 = ks * 32 + lg * 8;
      const float4* p = (const float4*)&agts[(size_t)row * 128 + k0];
      float4 a = p[0], b = p[1];
      bfx8 f;
      f[0] = (__bf16)a.x; f[1] = (__bf16)a.y; f[2] = (__bf16)a.z; f[3] = (__bf16)a.w;
      f[4] = (__bf16)b.x; f[5] = (__bf16)b.y; f[6] = (__bf16)b.z; f[7] = (__bf16)b.w;
      af[ks] = f;
    }
    f32x4 acc[8];
#pragma unroll
    for (int t = 0; t < 8; ++t) acc[t] = 0.f;
    wave_gemm<false>(WqL, nullptr, af, acc, lg, lr);
    wave_gn(acc, g_q, b_q, lr, true);
    wave_stage(actL, acc, lg, lr);
#pragma unroll
    for (int t = 0; t < 8; ++t) acc[t] = 0.f;
    wave_gemm<true>(WcL, actL, nullptr, acc, lg, lr);
#pragma unroll
    for (int r = 0; r < 4; ++r) {
      int grow = base + 4 * lg + r;
      if (grow < N)
        *(uint4*)(qc + (size_t)grow * 128 + 8 * lr) = pack_row(acc, r);
    }
  }
}

// ---------------------------------------------------------------------------
// edge kernel: 2-deep pipelined gather (all-static register handling);
// segmented reduce.
// ---------------------------------------------------------------------------
__global__ __launch_bounds__(768, 3) void k_edge(
    const float* __restrict__ agt_ctrs, const float* __restrict__ ctx_ctrs,
    const uint2* __restrict__ hw,
    const float* __restrict__ W_d1, const float* __restrict__ b_d1,
    const float* __restrict__ g_d2, const float* __restrict__ b_d2,
    const float* __restrict__ g_c1, const float* __restrict__ b_c1,
    const unsigned short* __restrict__ wsW,
    const unsigned short* __restrict__ qc, const unsigned short* __restrict__ cc,
    unsigned short* __restrict__ S, int E) {
  __shared__ __align__(16) char lds[114688];
  char* Wd2L = lds;
  char* Wc1L = lds + 32768;
  int tid = threadIdx.x, wid = tid >> 6, lane = tid & 63, lg = lane >> 4, lr = lane & 15;
  char* actL = lds + 65536 + wid * 4096;
  stage_w(wsW + 0 * 16384, Wd2L, tid, 768);
  stage_w(wsW + 1 * 16384, Wc1L, tid, 768);
  __syncthreads();
  int nTiles = (E + 15) >> 4;
  int stride = gridDim.x * 12;
  int tile = blockIdx.x * 12 + wid;
  if (tile >= nTiles) return;

  // ---- prologue: load cur tile's indices, gathers, ctrs
  int base = tile << 4;
  int er = base + lr;
  bool val = er < E;
  uint2 hwv = hw[val ? er : E - 1];
  int h = (int)hwv.x, w = (int)hwv.y;
  int nprev = (base > 0) ? (int)hw[base - 1].x : -1;
  int nnext = (base + 16 < E) ? (int)hw[base + 16].x : -1;
  uint4 qv0, qv1, qv2, qv3, cv0, cv1, cv2, cv3;
  {
    int h0 = __shfl(h, 4 * lg + 0, 64), w0 = __shfl(w, 4 * lg + 0, 64);
    int h1 = __shfl(h, 4 * lg + 1, 64), w1 = __shfl(w, 4 * lg + 1, 64);
    int h2 = __shfl(h, 4 * lg + 2, 64), w2 = __shfl(w, 4 * lg + 2, 64);
    int h3 = __shfl(h, 4 * lg + 3, 64), w3 = __shfl(w, 4 * lg + 3, 64);
    qv0 = *(const uint4*)(qc + (size_t)h0 * 128 + 8 * lr);
    qv1 = *(const uint4*)(qc + (size_t)h1 * 128 + 8 * lr);
    qv2 = *(const uint4*)(qc + (size_t)h2 * 128 + 8 * lr);
    qv3 = *(const uint4*)(qc + (size_t)h3 * 128 + 8 * lr);
    cv0 = *(const uint4*)(cc + (size_t)w0 * 128 + 8 * lr);
    cv1 = *(const uint4*)(cc + (size_t)w1 * 128 + 8 * lr);
    cv2 = *(const uint4*)(cc + (size_t)w2 * 128 + 8 * lr);
    cv3 = *(const uint4*)(cc + (size_t)w3 * 128 + 8 * lr);
  }
  float2 ac = *(const float2*)&agt_ctrs[2 * h];
  float2 cx = *(const float2*)&ctx_ctrs[2 * w];

  while (true) {
    int tnext = tile + stride;
    bool more = tnext < nTiles;
    // ---- prefetch next hw (latency hides under d1/GEMM1)
    uint2 hwn = hwv;
    int basen = base, nprevn = -1, nnextn = -1;
    bool valn = false;
    if (more) {
      basen = tnext << 4;
      int ern = basen + lr;
      valn = ern < E;
      hwn = hw[valn ? ern : E - 1];
      nprevn = (basen > 0) ? (int)hw[basen - 1].x : -1;
      nnextn = (basen + 16 < E) ? (int)hw[basen + 16].x : -1;
    }
    // ---- d1 = relu(dist @ W_d1 + b_d1); W_d1 rows reloaded (L1-hot, uniform)
    float dx = ac.x - cx.x, dy = ac.y - cx.y;
    bfx8 d1f[4];
#pragma unroll
    for (int ks = 0; ks < 4; ++ks) {
      int k0 = ks * 32 + lg * 8;
      float4 a0 = *(const float4*)&W_d1[k0], a1 = *(const float4*)&W_d1[k0 + 4];
      float4 b0 = *(const float4*)&W_d1[128 + k0], b1 = *(const float4*)&W_d1[128 + k0 + 4];
      float4 c0 = *(const float4*)&b_d1[k0], c1 = *(const float4*)&b_d1[k0 + 4];
      bfx8 f;
      f[0] = (__bf16)fmaxf(dx * a0.x + dy * b0.x + c0.x, 0.f);
      f[1] = (__bf16)fmaxf(dx * a0.y + dy * b0.y + c0.y, 0.f);
      f[2] = (__bf16)fmaxf(dx * a0.z + dy * b0.z + c0.z, 0.f);
      f[3] = (__bf16)fmaxf(dx * a0.w + dy * b0.w + c0.w, 0.f);
      f[4] = (__bf16)fmaxf(dx * a1.x + dy * b1.x + c1.x, 0.f);
      f[5] = (__bf16)fmaxf(dx * a1.y + dy * b1.y + c1.y, 0.f);
      f[6] = (__bf16)fmaxf(dx * a1.z + dy * b1.z + c1.z, 0.f);
      f[7] = (__bf16)fmaxf(dx * a1.w + dy * b1.w + c1.w, 0.f);
      d1f[ks] = f;
    }
    f32x4 acc[8];
#pragma unroll
    for (int t = 0; t < 8; ++t) acc[t] = 0.f;
    wave_gemm<false>(Wd2L, nullptr, d1f, acc, lg, lr);  // d1 @ W_d2
    wave_gn(acc, g_d2, b_d2, lr, true);
    wave_stage(actL, acc, lg, lr);
    // ---- prefetch next gathers + ctrs (hides under GEMM2/gn/reduce)
    int hn = (int)hwn.x, wn = (int)hwn.y;
    uint4 qn0, qn1, qn2, qn3, cn0, cn1, cn2, cn3;
    float2 acn = ac, cxn = cx;
    if (more) {
      int h0 = __shfl(hn, 4 * lg + 0, 64), w0 = __shfl(wn, 4 * lg + 0, 64);
      int h1 = __shfl(hn, 4 * lg + 1, 64), w1 = __shfl(wn, 4 * lg + 1, 64);
      int h2 = __shfl(hn, 4 * lg + 2, 64), w2 = __shfl(wn, 4 * lg + 2, 64);
      int h3 = __shfl(hn, 4 * lg + 3, 64), w3 = __shfl(wn, 4 * lg + 3, 64);
      qn0 = *(const uint4*)(qc + (size_t)h0 * 128 + 8 * lr);
      qn1 = *(const uint4*)(qc + (size_t)h1 * 128 + 8 * lr);
      qn2 = *(const uint4*)(qc + (size_t)h2 * 128 + 8 * lr);
      qn3 = *(const uint4*)(qc + (size_t)h3 * 128 + 8 * lr);
      cn0 = *(const uint4*)(cc + (size_t)w0 * 128 + 8 * lr);
      cn1 = *(const uint4*)(cc + (size_t)w1 * 128 + 8 * lr);
      cn2 = *(const uint4*)(cc + (size_t)w2 * 128 + 8 * lr);
      cn3 = *(const uint4*)(cc + (size_t)w3 * 128 + 8 * lr);
      acn = *(const float2*)&agt_ctrs[2 * hn];
      cxn = *(const float2*)&ctx_ctrs[2 * wn];
    }
    // ---- acc init = QC[h] + CC[w]: fully static member access (no scratch)
    ACC_INIT_ROW(0, qv0, cv0)
    ACC_INIT_ROW(1, qv1, cv1)
    ACC_INIT_ROW(2, qv2, cv2)
    ACC_INIT_ROW(3, qv3, cv3)
    wave_gemm<true>(Wc1L, actL, nullptr, acc, lg, lr);  // += d2 @ W_c1_top
    wave_gn(acc, g_c1, b_c1, lr, true);                 // h message
    wave_stage(actL, acc, lg, lr);
    // ---- segmented reduce; lane owns cols 2*lane, 2*lane+1
    {
      int nmy = val ? h : -1;
      float s0 = 0.f, s1 = 0.f;
      int curn = -1, seg_start = 0;
#pragma unroll
      for (int r = 0; r <= 16; ++r) {
        int n = (r < 16) ? __shfl(nmy, r, 64) : -2;
        if (n != curn) {
          if (curn >= 0) {
            bool aS = (seg_start == 0) && (curn == nprev);
            bool aE = (r == 16) && (curn == nnext);
            unsigned pkv = pkpair(s0, s1);
            unsigned short* addr = S + (size_t)curn * 128 + 2 * lane;
            if (aS || aE) atomAddBf2(addr, pkv);
            else *(unsigned*)addr = pkv;
          }
          curn = n; seg_start = r; s0 = 0.f; s1 = 0.f;
        }
        if (r < 16 && n >= 0) {
          unsigned hv = *(const unsigned*)(actL + swzb(r, 4 * lane));
          s0 += bfu2f((unsigned short)(hv & 0xffffu));
          s1 += bfu2f((unsigned short)(hv >> 16));
        }
      }
    }
    if (!more) break;
    // ---- rotate pipeline state (named registers only)
    tile = tnext; base = basen; val = valn; hwv = hwn;
    h = hn; w = wn; nprev = nprevn; nnext = nnextn;
    qv0 = qn0; qv1 = qn1; qv2 = qn2; qv3 = qn3;
    cv0 = cn0; cv1 = cn1; cv2 = cn2; cv3 = cn3;
    ac = acn; cx = cxn;
  }
}

// ---------------------------------------------------------------------------
// final: a = agts@W_a + S@W_c2; relu(gn(.)) @ W_l -> gn -> relu(+res)
// ---------------------------------------------------------------------------
__global__ __launch_bounds__(768, 3) void k_final(const float* __restrict__ agts,
                                                  const float* __restrict__ g_n,
                                                  const float* __restrict__ b_n,
                                                  const float* __restrict__ g_l,
                                                  const float* __restrict__ b_l,
                                                  const unsigned short* __restrict__ wsW,
                                                  const unsigned short* __restrict__ S,
                                                  float* __restrict__ out, int N) {
  __shared__ __align__(16) char lds[147456];
  char* WaL = lds;
  char* Wc2L = lds + 32768;
  char* WlL = lds + 65536;
  int tid = threadIdx.x, wid = tid >> 6, lane = tid & 63, lg = lane >> 4, lr = lane & 15;
  char* actL = lds + 98304 + wid * 4096;
  stage_w(wsW + 6 * 16384, WaL, tid, 768);
  stage_w(wsW + 4 * 16384, Wc2L, tid, 768);
  stage_w(wsW + 7 * 16384, WlL, tid, 768);
  __syncthreads();
  int nTiles = (N + 15) >> 4;
  int stride = gridDim.x * 12;
  for (int tile = blockIdx.x * 12 + wid; tile < nTiles; tile += stride) {
    int base = tile << 4;
    int row = base + lr; if (row >= N) row = N - 1;
    bfx8 af[4], sf[4];
#pragma unroll
    for (int ks = 0; ks < 4; ++ks) {
      int k0 = ks * 32 + lg * 8;
      const float4* p = (const float4*)&agts[(size_t)row * 128 + k0];
      float4 a = p[0], b = p[1];
      bfx8 f;
      f[0] = (__bf16)a.x; f[1] = (__bf16)a.y; f[2] = (__bf16)a.z; f[3] = (__bf16)a.w;
      f[4] = (__bf16)b.x; f[5] = (__bf16)b.y; f[6] = (__bf16)b.z; f[7] = (__bf16)b.w;
      af[ks] = f;
      sf[ks] = *(const bfx8*)&S[(size_t)row * 128 + k0];
    }
    f32x4 acc[8];
#pragma unroll
    for (int t = 0; t < 8; ++t) acc[t] = 0.f;
    wave_gemm<false>(WaL, nullptr, af, acc, lg, lr);
    wave_gemm<false>(Wc2L, nullptr, sf, acc, lg, lr);
    wave_gn(acc, g_n, b_n, lr, true);
    wave_stage(actL, acc, lg, lr);
#pragma unroll
    for (int t = 0; t < 8; ++t) acc[t] = 0.f;
    wave_gemm<true>(WlL, actL, nullptr, acc, lg, lr);
    wave_gn(acc, g_l, b_l, lr, false);
#pragma unroll
    for (int r = 0; r < 4; ++r) {
      int grow = base + 4 * lg + r;
      if (grow < N) {
#pragma unroll
        for (int t = 0; t < 8; ++t) {
          int c = t * 16 + lr;
          float res = agts[(size_t)grow * 128 + c];
          out[(size_t)grow * 128 + c] = fmaxf(acc[t][r] + res, 0.f);
        }
      }
    }
  }
}

// ---------------------------------------------------------------------------
extern "C" void kernel_launch(void* const* d_in, const int* in_sizes, int n_in,
                              void* d_out, int out_size, void* d_ws, size_t ws_size,
                              hipStream_t stream) {
  const float* agts = (const float*)d_in[0];
  const float* ctx = (const float*)d_in[1];
  const float* agt_ctrs = (const float*)d_in[2];
  const float* ctx_ctrs = (const float*)d_in[3];
  const int* hi = (const int*)d_in[4];
  const int* wi = (const int*)d_in[5];
  const float* W_d1 = (const float*)d_in[6];
  const float* b_d1 = (const float*)d_in[7];
  const float* W_d2 = (const float*)d_in[8];
  const float* g_d2 = (const float*)d_in[9];
  const float* b_d2 = (const float*)d_in[10];
  const float* W_q = (const float*)d_in[11];
  const float* g_q = (const float*)d_in[12];
  const float* b_q = (const float*)d_in[13];
  const float* W_c1 = (const float*)d_in[14];
  const float* g_c1 = (const float*)d_in[15];
  const float* b_c1 = (const float*)d_in[16];
  const float* W_c2 = (const float*)d_in[17];
  const float* W_a = (const float*)d_in[18];
  const float* g_n = (const float*)d_in[19];
  const float* b_n = (const float*)d_in[20];
  const float* W_l = (const float*)d_in[21];
  const float* g_l = (const float*)d_in[22];
  const float* b_l = (const float*)d_in[23];

  int N = in_sizes[0] / 128;
  int M = in_sizes[1] / 128;
  int E = in_sizes[4];

  float* out = (float*)d_out;
  char* ws = (char*)d_ws;
  size_t o = 0;
  unsigned short* qcP = (unsigned short*)(ws + o); o += (size_t)N * 256;
  unsigned short* ccP = (unsigned short*)(ws + o); o += (size_t)M * 256;
  unsigned short* Sp  = (unsigned short*)(ws + o); o += (size_t)N * 256;
  unsigned short* wsW = (unsigned short*)(ws + o); o += 262144;
  int* cnt  = (int*)(ws + o); o += ((size_t)N * 4 + 255) & ~255ull;
  int* baseA= (int*)(ws + o); o += ((size_t)N * 4 + 255) & ~255ull;
  int* rank = (int*)(ws + o); o += ((size_t)E * 4 + 255) & ~255ull;
  int* bsum = (int*)(ws + o); o += 8192;
  uint2* hwP = (uint2*)(ws + o); o += ((size_t)E * 8 + 255) & ~255ull;

  int nb = (N + 1023) / 1024;

  hipMemsetAsync(cnt, 0, (size_t)N * 4, stream);
  hipMemsetAsync(Sp, 0, (size_t)N * 256, stream);
  k_prep_weights<<<8, 256, 0, stream>>>(W_d2, W_c1, W_c2, W_q, W_a, W_l, wsW);
  k_hist<<<(E + 255) / 256, 256, 0, stream>>>(hi, cnt, rank, E);
  k_scan1<<<nb, 256, 0, stream>>>(cnt, bsum, N);
  k_scan2<<<1, 1024, 0, stream>>>(bsum, nb);
  k_scan3<<<nb, 256, 0, stream>>>(cnt, bsum, baseA, N);
  k_fill<<<(E + 255) / 256, 256, 0, stream>>>(hi, wi, baseA, rank, hwP, E);
  k_ctx<<<256, 768, 0, stream>>>(ctx, wsW, ccP, M);
  k_agents<<<256, 768, 0, stream>>>(agts, g_q, b_q, wsW, qcP, N);
  k_edge<<<256, 768, 0, stream>>>(agt_ctrs, ctx_ctrs, hwP, W_d1, b_d1,
                                  g_d2, b_d2, g_c1, b_c1, wsW, qcP, ccP, Sp, E);
  k_final<<<256, 768, 0, stream>>>(agts, g_n, b_n, g_l, b_l, wsW, Sp, out, N);
}

// Round 8
// 561.227 us; speedup vs baseline: 1.0880x; 1.0880x over previous
//
#include <hip/hip_runtime.h>
#include <hip/hip_bf16.h>
#include <stdint.h>

// ---------------------------------------------------------------------------
// Round 8: register-lean edge kernel (R3 structure) + permuted-layout QCC
// gather through LDS (uint4 all the way), cheap CSR chain, native bf16 casts.
//  R6/R7 lesson: allocator pins VGPR at 84 and spills ALL extra live state to
//  scratch (~59 dwords/lane/tile = the exact 464MB WRITE). So gather state
//  must live in LDS, not registers; no software pipeline.
// ---------------------------------------------------------------------------

typedef __bf16 bfx8 __attribute__((ext_vector_type(8)));
typedef float f32x4 __attribute__((ext_vector_type(4)));
typedef short s16x2 __attribute__((ext_vector_type(2)));

__device__ __forceinline__ unsigned short bfbits(float f) {
  __bf16 b = (__bf16)f;
  return __builtin_bit_cast(unsigned short, b);
}
__device__ __forceinline__ float bfu2f(unsigned short u) {
  return __builtin_bit_cast(float, ((unsigned)u) << 16);
}
__device__ __forceinline__ unsigned pkpair(float a, float b) {
  return (unsigned)bfbits(a) | ((unsigned)bfbits(b) << 16);
}
__device__ __forceinline__ unsigned pk2(unsigned x, unsigned y) {
  float lo = bfu2f((unsigned short)(x & 0xffffu)) + bfu2f((unsigned short)(y & 0xffffu));
  float hi = bfu2f((unsigned short)(x >> 16)) + bfu2f((unsigned short)(y >> 16));
  return pkpair(lo, hi);
}

__device__ __forceinline__ void atomAddBf2(unsigned short* p, unsigned v) {
#if defined(__has_builtin) && __has_builtin(__builtin_amdgcn_global_atomic_fadd_v2bf16)
  __builtin_amdgcn_global_atomic_fadd_v2bf16(
      (__attribute__((address_space(1))) s16x2*)p, __builtin_bit_cast(s16x2, v));
#else
  unsigned* q = (unsigned*)p;
  unsigned old = *q;
  while (true) {
    unsigned nv = pk2(old, v);
    unsigned prev = atomicCAS(q, old, nv);
    if (prev == old) break;
    old = prev;
  }
#endif
}

// swizzled byte offset of element (row, kbyte) in a [rows][128] bf16 LDS tile
__device__ __forceinline__ int swzb(int row, int kbyte) {
  return (row * 256 + kbyte) ^ ((row & 7) << 4);
}

// linear copy of one pre-swizzled transposed weight (32768 B) into LDS
__device__ __forceinline__ void stage_w(const unsigned short* wsrc, char* dst, int tid, int nth) {
  const uint4* s = (const uint4*)wsrc;
  uint4* d = (uint4*)dst;
  for (int i = tid; i < 2048; i += nth) d[i] = s[i];
}

// wave GEMM: [16 rows x 128] @ [128 x 128] -> acc[8] tiles (16x16), accumulate
template <bool A_FROM_LDS>
__device__ __forceinline__ void wave_gemm(const char* WtL, const char* XL,
                                          const bfx8* aF, f32x4 acc[8],
                                          int lg, int lr) {
#pragma unroll
  for (int ks = 0; ks < 4; ++ks) {
    bfx8 a;
    if (A_FROM_LDS)
      a = *(const bfx8*)(XL + swzb(lr, (ks * 32 + lg * 8) * 2));
    else
      a = aF[ks];
#pragma unroll
    for (int t = 0; t < 8; ++t) {
      int n = t * 16 + lr;
      bfx8 b = *(const bfx8*)(WtL + swzb(n, (ks * 32 + lg * 8) * 2));
      acc[t] = __builtin_amdgcn_mfma_f32_16x16x32_bf16(a, b, acc[t], 0, 0, 0);
    }
  }
}

// in-register GroupNorm(1 group over 128 ch); gamma/beta loaded per call (L1)
__device__ __forceinline__ void wave_gn(f32x4 acc[8], const float* __restrict__ g,
                                        const float* __restrict__ b, int lr, bool do_relu) {
  float s0 = 0.f, s1 = 0.f, s2 = 0.f, s3 = 0.f;
  float q0 = 0.f, q1 = 0.f, q2 = 0.f, q3 = 0.f;
#pragma unroll
  for (int t = 0; t < 8; ++t) {
    float v0 = acc[t][0], v1 = acc[t][1], v2 = acc[t][2], v3 = acc[t][3];
    s0 += v0; q0 += v0 * v0;
    s1 += v1; q1 += v1 * v1;
    s2 += v2; q2 += v2 * v2;
    s3 += v3; q3 += v3 * v3;
  }
#pragma unroll
  for (int m = 1; m <= 8; m <<= 1) {
    s0 += __shfl_xor(s0, m, 64); q0 += __shfl_xor(q0, m, 64);
    s1 += __shfl_xor(s1, m, 64); q1 += __shfl_xor(q1, m, 64);
    s2 += __shfl_xor(s2, m, 64); q2 += __shfl_xor(q2, m, 64);
    s3 += __shfl_xor(s3, m, 64); q3 += __shfl_xor(q3, m, 64);
  }
  float mean[4], rstd[4];
  {
    const float inv = 1.f / 128.f;
    float m0 = s0 * inv, m1 = s1 * inv, m2 = s2 * inv, m3 = s3 * inv;
    mean[0] = m0; mean[1] = m1; mean[2] = m2; mean[3] = m3;
    rstd[0] = rsqrtf(q0 * inv - m0 * m0 + 1e-5f);
    rstd[1] = rsqrtf(q1 * inv - m1 * m1 + 1e-5f);
    rstd[2] = rsqrtf(q2 * inv - m2 * m2 + 1e-5f);
    rstd[3] = rsqrtf(q3 * inv - m3 * m3 + 1e-5f);
  }
#pragma unroll
  for (int t = 0; t < 8; ++t) {
    float gc = g[t * 16 + lr], bc = b[t * 16 + lr];
#pragma unroll
    for (int r = 0; r < 4; ++r) {
      float v = (acc[t][r] - mean[r]) * rstd[r] * gc + bc;
      if (do_relu) v = fmaxf(v, 0.f);
      acc[t][r] = v;
    }
  }
}

// write post-GN tile (C-layout) into wave-private swizzled LDS stage as bf16
__device__ __forceinline__ void wave_stage(char* XL, const f32x4 acc[8], int lg, int lr) {
#pragma unroll
  for (int t = 0; t < 8; ++t) {
#pragma unroll
    for (int r = 0; r < 4; ++r) {
      int row = 4 * lg + r, c = t * 16 + lr;
      *(__bf16*)(XL + swzb(row, 2 * c)) = (__bf16)acc[t][r];
    }
  }
}

// pack 8 acc t-values of row r into a uint4 (for permuted qc/cc stores)
__device__ __forceinline__ uint4 pack_row(const f32x4 acc[8], int r) {
  uint4 o;
  o.x = pkpair(acc[0][r], acc[1][r]);
  o.y = pkpair(acc[2][r], acc[3][r]);
  o.z = pkpair(acc[4][r], acc[5][r]);
  o.w = pkpair(acc[6][r], acc[7][r]);
  return o;
}

// ---------------------------------------------------------------------------
// prep: transpose + bf16-convert + pre-swizzle the 8 [128x128] weights
// order: 0 W_d2, 1 W_c1_top, 2 W_c1_mid, 3 W_c1_bot, 4 W_c2, 5 W_q, 6 W_a, 7 W_l
// ---------------------------------------------------------------------------
__global__ void k_prep_weights(const float* Wd2, const float* Wc1, const float* Wc2,
                               const float* Wq, const float* Wa, const float* Wl,
                               unsigned short* wsW) {
  __shared__ unsigned short tmp[128 * 128];
  int m = blockIdx.x;
  const float* src;
  switch (m) {
    case 0: src = Wd2; break;
    case 1: src = Wc1; break;
    case 2: src = Wc1 + 128 * 128; break;
    case 3: src = Wc1 + 256 * 128; break;
    case 4: src = Wc2; break;
    case 5: src = Wq; break;
    case 6: src = Wa; break;
    default: src = Wl; break;
  }
  int tid = threadIdx.x;
#pragma unroll
  for (int i = 0; i < 16; ++i) {
    int lin = i * 256 + tid;
    float4 v = ((const float4*)src)[lin];
    ushort4 b;
    b.x = bfbits(v.x); b.y = bfbits(v.y); b.z = bfbits(v.z); b.w = bfbits(v.w);
    *(ushort4*)&tmp[lin * 4] = b;
  }
  __syncthreads();
  unsigned short* dst = wsW + (size_t)m * 16384;
#pragma unroll
  for (int i = 0; i < 16; ++i) {
    int lin = i * 256 + tid;
    int n = lin >> 5, q = lin & 31, k0 = q * 4;
    ushort4 b;
    b.x = tmp[(k0 + 0) * 128 + n];
    b.y = tmp[(k0 + 1) * 128 + n];
    b.z = tmp[(k0 + 2) * 128 + n];
    b.w = tmp[(k0 + 3) * 128 + n];
    *(ushort4*)((char*)dst + swzb(n, k0 * 2)) = b;
  }
}

// ---------------------------------------------------------------------------
// CSR build: rank-hist -> hierarchical scan -> fill (no atomics in fill)
// ---------------------------------------------------------------------------
__global__ void k_hist(const int* __restrict__ hi, int* cnt, int* rank, int E) {
  int e = blockIdx.x * 256 + threadIdx.x;
  if (e < E) rank[e] = atomicAdd(&cnt[hi[e]], 1);
}

__global__ void k_scan1(const int* __restrict__ cnt, int* bsum, int N) {
  __shared__ int red[256];
  int b = blockIdx.x, t = threadIdx.x;
  int i0 = b * 1024 + t * 4;
  int s = 0;
#pragma unroll
  for (int j = 0; j < 4; ++j) { int i = i0 + j; if (i < N) s += cnt[i]; }
  red[t] = s;
  __syncthreads();
  for (int d = 128; d > 0; d >>= 1) {
    if (t < d) red[t] += red[t + d];
    __syncthreads();
  }
  if (t == 0) bsum[b] = red[0];
}

__global__ __launch_bounds__(1024) void k_scan2(int* bsum, int nb) {
  __shared__ int sh[1024];
  int t = threadIdx.x;
  sh[t] = (t < nb) ? bsum[t] : 0;
  __syncthreads();
  for (int d = 1; d < 1024; d <<= 1) {
    int v = (t >= d) ? sh[t - d] : 0;
    __syncthreads();
    sh[t] += v;
    __syncthreads();
  }
  if (t < nb) bsum[t] = (t == 0) ? 0 : sh[t - 1];
}

__global__ void k_scan3(const int* __restrict__ cnt, const int* __restrict__ bsum,
                        int* base, int N) {
  __shared__ int tsum[256];
  int b = blockIdx.x, t = threadIdx.x;
  int i0 = b * 1024 + t * 4;
  int v[4]; int s = 0;
#pragma unroll
  for (int j = 0; j < 4; ++j) { int i = i0 + j; v[j] = (i < N) ? cnt[i] : 0; s += v[j]; }
  tsum[t] = s;
  __syncthreads();
  for (int d = 1; d < 256; d <<= 1) {
    int x = (t >= d) ? tsum[t - d] : 0;
    __syncthreads();
    tsum[t] += x;
    __syncthreads();
  }
  int off = bsum[b] + ((t == 0) ? 0 : tsum[t - 1]);
#pragma unroll
  for (int j = 0; j < 4; ++j) {
    int i = i0 + j;
    if (i < N) { base[i] = off; off += v[j]; }
  }
}

__global__ void k_fill(const int* __restrict__ hi, const int* __restrict__ wi,
                       const int* __restrict__ base, const int* __restrict__ rank,
                       uint2* hw, int E) {
  int e = blockIdx.x * 256 + threadIdx.x;
  if (e < E) {
    int h = hi[e];
    int p = base[h] + rank[e];
    hw[p] = make_uint2((unsigned)h, (unsigned)wi[e]);
  }
}

// ---------------------------------------------------------------------------
// ctx precompute: CC = ctx @ W_c1_bot, stored PERMUTED (row pos 8*lr+t)
// ---------------------------------------------------------------------------
__global__ __launch_bounds__(768, 3) void k_ctx(const float* __restrict__ ctx,
                                                const unsigned short* __restrict__ wsW,
                                                unsigned short* __restrict__ cc, int M) {
  __shared__ __align__(16) char lds[32768];
  int tid = threadIdx.x, wid = tid >> 6, lane = tid & 63, lg = lane >> 4, lr = lane & 15;
  stage_w(wsW + 3 * 16384, lds, tid, 768);
  __syncthreads();
  int nTiles = (M + 15) >> 4;
  int stride = gridDim.x * 12;
  for (int tile = blockIdx.x * 12 + wid; tile < nTiles; tile += stride) {
    int base = tile << 4;
    int row = base + lr; if (row >= M) row = M - 1;
    bfx8 cf[4];
#pragma unroll
    for (int ks = 0; ks < 4; ++ks) {
      int k0 = ks * 32 + lg * 8;
      const float4* p = (const float4*)&ctx[(size_t)row * 128 + k0];
      float4 a = p[0], b = p[1];
      bfx8 f;
      f[0] = (__bf16)a.x; f[1] = (__bf16)a.y; f[2] = (__bf16)a.z; f[3] = (__bf16)a.w;
      f[4] = (__bf16)b.x; f[5] = (__bf16)b.y; f[6] = (__bf16)b.z; f[7] = (__bf16)b.w;
      cf[ks] = f;
    }
    f32x4 acc[8];
#pragma unroll
    for (int t = 0; t < 8; ++t) acc[t] = 0.f;
    wave_gemm<false>(lds, nullptr, cf, acc, lg, lr);
#pragma unroll
    for (int r = 0; r < 4; ++r) {
      int grow = base + 4 * lg + r;
      if (grow < M)
        *(uint4*)(cc + (size_t)grow * 128 + 8 * lr) = pack_row(acc, r);
    }
  }
}

// ---------------------------------------------------------------------------
// agent precompute: QC = relu(gn(agts@W_q))@W_c1_mid, stored PERMUTED
// ---------------------------------------------------------------------------
__global__ __launch_bounds__(768, 3) void k_agents(const float* __restrict__ agts,
                                                   const float* __restrict__ g_q,
                                                   const float* __restrict__ b_q,
                                                   const unsigned short* __restrict__ wsW,
                                                   unsigned short* __restrict__ qc, int N) {
  __shared__ __align__(16) char lds[114688];
  char* WqL = lds;
  char* WcL = lds + 32768;
  int tid = threadIdx.x, wid = tid >> 6, lane = tid & 63, lg = lane >> 4, lr = lane & 15;
  char* actL = lds + 65536 + wid * 4096;
  stage_w(wsW + 5 * 16384, WqL, tid, 768);
  stage_w(wsW + 2 * 16384, WcL, tid, 768);
  __syncthreads();
  int nTiles = (N + 15) >> 4;
  int stride = gridDim.x * 12;
  for (int tile = blockIdx.x * 12 + wid; tile < nTiles; tile += stride) {
    int base = tile << 4;
    int row = base + lr; if (row >= N) row = N - 1;
    bfx8 af[4];
#pragma unroll
    for (int ks = 0; ks < 4; ++ks) {
      int k0 = ks * 32 + lg * 8;
      const float4* p = (const float4*)&agts[(size_t)row * 128 + k0];
      float4 a = p[0], b = p[1];
      bfx8 f;
      f[0] = (__bf16)a.x; f[1] = (__bf16)a.y; f[2] = (__bf16)a.z; f[3] = (__bf16)a.w;
      f[4] = (__bf16)b.x; f[5] = (__bf16)b.y; f[6] = (__bf16)b.z; f[7] = (__bf16)b.w;
      af[ks] = f;
    }
    f32x4 acc[8];
#pragma unroll
    for (int t = 0; t < 8; ++t) acc[t] = 0.f;
    wave_gemm<false>(WqL, nullptr, af, acc, lg, lr);
    wave_gn(acc, g_q, b_q, lr, true);
    wave_stage(actL, acc, lg, lr);
#pragma unroll
    for (int t = 0; t < 8; ++t) acc[t] = 0.f;
    wave_gemm<true>(WcL, actL, nullptr, acc, lg, lr);
#pragma unroll
    for (int r = 0; r < 4; ++r) {
      int grow = base + 4 * lg + r;
      if (grow < N)
        *(uint4*)(qc + (size_t)grow * 128 + 8 * lr) = pack_row(acc, r);
    }
  }
}

// ---------------------------------------------------------------------------
// edge kernel: LDS QCC gather (uint4 permuted rows), no pipeline, register-
// lean; segmented reduce with boundary atomics.
// ---------------------------------------------------------------------------
__global__ __launch_bounds__(768) void k_edge(
    const float* __restrict__ agt_ctrs, const float* __restrict__ ctx_ctrs,
    const uint2* __restrict__ hw,
    const float* __restrict__ W_d1, const float* __restrict__ b_d1,
    const float* __restrict__ g_d2, const float* __restrict__ b_d2,
    const float* __restrict__ g_c1, const float* __restrict__ b_c1,
    const unsigned short* __restrict__ wsW,
    const unsigned short* __restrict__ qc, const unsigned short* __restrict__ cc,
    unsigned short* __restrict__ S, int E) {
  __shared__ __align__(16) char lds[163840];
  char* Wd2L = lds;
  char* Wc1L = lds + 32768;
  int tid = threadIdx.x, wid = tid >> 6, lane = tid & 63, lg = lane >> 4, lr = lane & 15;
  char* QCCL = lds + 65536 + wid * 8192;  // 4KB permuted-uint4 QCC rows
  char* actL = QCCL + 4096;               // 4KB swizzled act stage
  stage_w(wsW + 0 * 16384, Wd2L, tid, 768);
  stage_w(wsW + 1 * 16384, Wc1L, tid, 768);
  __syncthreads();
  int nTiles = (E + 15) >> 4;
  int stride = gridDim.x * 12;
  for (int tile = blockIdx.x * 12 + wid; tile < nTiles; tile += stride) {
    int base = tile << 4;
    // ---- QCC gather: row gr = lane>>2, 64B chunk gq = lane&3 (transient regs)
    {
      int gr = lane >> 2, gq = lane & 3;
      int ge = base + gr; if (ge >= E) ge = E - 1;
      uint2 ghw = hw[ge];
      const uint4* qrow = (const uint4*)(qc + (size_t)ghw.x * 128) + gq * 4;
      const uint4* crow = (const uint4*)(cc + (size_t)ghw.y * 128) + gq * 4;
#pragma unroll
      for (int i = 0; i < 4; ++i) {
        uint4 av = qrow[i], bv = crow[i];
        uint4 o;
        o.x = pk2(av.x, bv.x); o.y = pk2(av.y, bv.y);
        o.z = pk2(av.z, bv.z); o.w = pk2(av.w, bv.w);
        *(uint4*)(QCCL + gr * 256 + gq * 64 + i * 16) = o;
      }
    }
    // ---- per-lane edge indices for d1 + segmented reduce
    int er = base + lr;
    bool val = er < E;
    uint2 hwv = hw[val ? er : E - 1];
    int h = (int)hwv.x, w = (int)hwv.y;
    // ---- d1 = relu(dist @ W_d1 + b_d1); W rows reloaded per tile (L1-hot)
    float dx, dy;
    {
      float2 ac2 = *(const float2*)&agt_ctrs[2 * h];
      float2 cx2 = *(const float2*)&ctx_ctrs[2 * w];
      dx = ac2.x - cx2.x; dy = ac2.y - cx2.y;
    }
    bfx8 d1f[4];
#pragma unroll
    for (int ks = 0; ks < 4; ++ks) {
      int k0 = ks * 32 + lg * 8;
      float4 a0 = *(const float4*)&W_d1[k0], a1 = *(const float4*)&W_d1[k0 + 4];
      float4 b0 = *(const float4*)&W_d1[128 + k0], b1 = *(const float4*)&W_d1[128 + k0 + 4];
      float4 c0 = *(const float4*)&b_d1[k0], c1 = *(const float4*)&b_d1[k0 + 4];
      bfx8 f;
      f[0] = (__bf16)fmaxf(dx * a0.x + dy * b0.x + c0.x, 0.f);
      f[1] = (__bf16)fmaxf(dx * a0.y + dy * b0.y + c0.y, 0.f);
      f[2] = (__bf16)fmaxf(dx * a0.z + dy * b0.z + c0.z, 0.f);
      f[3] = (__bf16)fmaxf(dx * a0.w + dy * b0.w + c0.w, 0.f);
      f[4] = (__bf16)fmaxf(dx * a1.x + dy * b1.x + c1.x, 0.f);
      f[5] = (__bf16)fmaxf(dx * a1.y + dy * b1.y + c1.y, 0.f);
      f[6] = (__bf16)fmaxf(dx * a1.z + dy * b1.z + c1.z, 0.f);
      f[7] = (__bf16)fmaxf(dx * a1.w + dy * b1.w + c1.w, 0.f);
      d1f[ks] = f;
    }
    f32x4 acc[8];
#pragma unroll
    for (int t = 0; t < 8; ++t) acc[t] = 0.f;
    wave_gemm<false>(Wd2L, nullptr, d1f, acc, lg, lr);  // d1 @ W_d2
    wave_gn(acc, g_d2, b_d2, lr, true);
    wave_stage(actL, acc, lg, lr);
    // ---- acc init = QCC rows (one b128 read per r, permuted layout)
#pragma unroll
    for (int r = 0; r < 4; ++r) {
      uint4 v = *(const uint4*)(QCCL + (4 * lg + r) * 256 + 16 * lr);
      acc[0][r] = bfu2f((unsigned short)(v.x & 0xffffu));
      acc[1][r] = bfu2f((unsigned short)(v.x >> 16));
      acc[2][r] = bfu2f((unsigned short)(v.y & 0xffffu));
      acc[3][r] = bfu2f((unsigned short)(v.y >> 16));
      acc[4][r] = bfu2f((unsigned short)(v.z & 0xffffu));
      acc[5][r] = bfu2f((unsigned short)(v.z >> 16));
      acc[6][r] = bfu2f((unsigned short)(v.w & 0xffffu));
      acc[7][r] = bfu2f((unsigned short)(v.w >> 16));
    }
    wave_gemm<true>(Wc1L, actL, nullptr, acc, lg, lr);  // += d2 @ W_c1_top
    wave_gn(acc, g_c1, b_c1, lr, true);                 // h message
    wave_stage(actL, acc, lg, lr);
    // ---- segmented reduce; lane owns cols 2*lane, 2*lane+1
    {
      int nprev = (base > 0) ? (int)hw[base - 1].x : -1;
      int nnext = (base + 16 < E) ? (int)hw[base + 16].x : -1;
      int nmy = val ? h : -1;
      float s0 = 0.f, s1 = 0.f;
      int curn = -1, seg_start = 0;
#pragma unroll
      for (int r = 0; r <= 16; ++r) {
        int n = (r < 16) ? __shfl(nmy, r, 64) : -2;
        if (n != curn) {
          if (curn >= 0) {
            bool aS = (seg_start == 0) && (curn == nprev);
            bool aE = (r == 16) && (curn == nnext);
            unsigned pkv = pkpair(s0, s1);
            unsigned short* addr = S + (size_t)curn * 128 + 2 * lane;
            if (aS || aE) atomAddBf2(addr, pkv);
            else *(unsigned*)addr = pkv;
          }
          curn = n; seg_start = r; s0 = 0.f; s1 = 0.f;
        }
        if (r < 16 && n >= 0) {
          unsigned hv = *(const unsigned*)(actL + swzb(r, 4 * lane));
          s0 += bfu2f((unsigned short)(hv & 0xffffu));
          s1 += bfu2f((unsigned short)(hv >> 16));
        }
      }
    }
  }
}

// ---------------------------------------------------------------------------
// final: a = agts@W_a + S@W_c2; relu(gn(.)) @ W_l -> gn -> relu(+res)
// ---------------------------------------------------------------------------
__global__ __launch_bounds__(768, 3) void k_final(const float* __restrict__ agts,
                                                  const float* __restrict__ g_n,
                                                  const float* __restrict__ b_n,
                                                  const float* __restrict__ g_l,
                                                  const float* __restrict__ b_l,
                                                  const unsigned short* __restrict__ wsW,
                                                  const unsigned short* __restrict__ S,
                                                  float* __restrict__ out, int N) {
  __shared__ __align__(16) char lds[147456];
  char* WaL = lds;
  char* Wc2L = lds + 32768;
  char* WlL = lds + 65536;
  int tid = threadIdx.x, wid = tid >> 6, lane = tid & 63, lg = lane >> 4, lr = lane & 15;
  char* actL = lds + 98304 + wid * 4096;
  stage_w(wsW + 6 * 16384, WaL, tid, 768);
  stage_w(wsW + 4 * 16384, Wc2L, tid, 768);
  stage_w(wsW + 7 * 16384, WlL, tid, 768);
  __syncthreads();
  int nTiles = (N + 15) >> 4;
  int stride = gridDim.x * 12;
  for (int tile = blockIdx.x * 12 + wid; tile < nTiles; tile += stride) {
    int base = tile << 4;
    int row = base + lr; if (row >= N) row = N - 1;
    bfx8 af[4], sf[4];
#pragma unroll
    for (int ks = 0; ks < 4; ++ks) {
      int k0 = ks * 32 + lg * 8;
      const float4* p = (const float4*)&agts[(size_t)row * 128 + k0];
      float4 a = p[0], b = p[1];
      bfx8 f;
      f[0] = (__bf16)a.x; f[1] = (__bf16)a.y; f[2] = (__bf16)a.z; f[3] = (__bf16)a.w;
      f[4] = (__bf16)b.x; f[5] = (__bf16)b.y; f[6] = (__bf16)b.z; f[7] = (__bf16)b.w;
      af[ks] = f;
      sf[ks] = *(const bfx8*)&S[(size_t)row * 128 + k0];
    }
    f32x4 acc[8];
#pragma unroll
    for (int t = 0; t < 8; ++t) acc[t] = 0.f;
    wave_gemm<false>(WaL, nullptr, af, acc, lg, lr);
    wave_gemm<false>(Wc2L, nullptr, sf, acc, lg, lr);
    wave_gn(acc, g_n, b_n, lr, true);
    wave_stage(actL, acc, lg, lr);
#pragma unroll
    for (int t = 0; t < 8; ++t) acc[t] = 0.f;
    wave_gemm<true>(WlL, actL, nullptr, acc, lg, lr);
    wave_gn(acc, g_l, b_l, lr, false);
#pragma unroll
    for (int r = 0; r < 4; ++r) {
      int grow = base + 4 * lg + r;
      if (grow < N) {
#pragma unroll
        for (int t = 0; t < 8; ++t) {
          int c = t * 16 + lr;
          float res = agts[(size_t)grow * 128 + c];
          out[(size_t)grow * 128 + c] = fmaxf(acc[t][r] + res, 0.f);
        }
      }
    }
  }
}

// ---------------------------------------------------------------------------
extern "C" void kernel_launch(void* const* d_in, const int* in_sizes, int n_in,
                              void* d_out, int out_size, void* d_ws, size_t ws_size,
                              hipStream_t stream) {
  const float* agts = (const float*)d_in[0];
  const float* ctx = (const float*)d_in[1];
  const float* agt_ctrs = (const float*)d_in[2];
  const float* ctx_ctrs = (const float*)d_in[3];
  const int* hi = (const int*)d_in[4];
  const int* wi = (const int*)d_in[5];
  const float* W_d1 = (const float*)d_in[6];
  const float* b_d1 = (const float*)d_in[7];
  const float* W_d2 = (const float*)d_in[8];
  const float* g_d2 = (const float*)d_in[9];
  const float* b_d2 = (const float*)d_in[10];
  const float* W_q = (const float*)d_in[11];
  const float* g_q = (const float*)d_in[12];
  const float* b_q = (const float*)d_in[13];
  const float* W_c1 = (const float*)d_in[14];
  const float* g_c1 = (const float*)d_in[15];
  const float* b_c1 = (const float*)d_in[16];
  const float* W_c2 = (const float*)d_in[17];
  const float* W_a = (const float*)d_in[18];
  const float* g_n = (const float*)d_in[19];
  const float* b_n = (const float*)d_in[20];
  const float* W_l = (const float*)d_in[21];
  const float* g_l = (const float*)d_in[22];
  const float* b_l = (const float*)d_in[23];

  int N = in_sizes[0] / 128;
  int M = in_sizes[1] / 128;
  int E = in_sizes[4];

  float* out = (float*)d_out;
  char* ws = (char*)d_ws;
  size_t o = 0;
  unsigned short* qcP = (unsigned short*)(ws + o); o += (size_t)N * 256;
  unsigned short* ccP = (unsigned short*)(ws + o); o += (size_t)M * 256;
  unsigned short* Sp  = (unsigned short*)(ws + o); o += (size_t)N * 256;
  unsigned short* wsW = (unsigned short*)(ws + o); o += 262144;
  int* cnt  = (int*)(ws + o); o += ((size_t)N * 4 + 255) & ~255ull;
  int* baseA= (int*)(ws + o); o += ((size_t)N * 4 + 255) & ~255ull;
  int* rank = (int*)(ws + o); o += ((size_t)E * 4 + 255) & ~255ull;
  int* bsum = (int*)(ws + o); o += 8192;
  uint2* hwP = (uint2*)(ws + o); o += ((size_t)E * 8 + 255) & ~255ull;

  int nb = (N + 1023) / 1024;

  hipMemsetAsync(cnt, 0, (size_t)N * 4, stream);
  hipMemsetAsync(Sp, 0, (size_t)N * 256, stream);
  k_prep_weights<<<8, 256, 0, stream>>>(W_d2, W_c1, W_c2, W_q, W_a, W_l, wsW);
  k_hist<<<(E + 255) / 256, 256, 0, stream>>>(hi, cnt, rank, E);
  k_scan1<<<nb, 256, 0, stream>>>(cnt, bsum, N);
  k_scan2<<<1, 1024, 0, stream>>>(bsum, nb);
  k_scan3<<<nb, 256, 0, stream>>>(cnt, bsum, baseA, N);
  k_fill<<<(E + 255) / 256, 256, 0, stream>>>(hi, wi, baseA, rank, hwP, E);
  k_ctx<<<256, 768, 0, stream>>>(ctx, wsW, ccP, M);
  k_agents<<<256, 768, 0, stream>>>(agts, g_q, b_q, wsW, qcP, N);
  k_edge<<<256, 768, 0, stream>>>(agt_ctrs, ctx_ctrs, hwP, W_d1, b_d1,
                                  g_d2, b_d2, g_c1, b_c1, wsW, qcP, ccP, Sp, E);
  k_final<<<256, 768, 0, stream>>>(agts, g_n, b_n, g_l, b_l, wsW, Sp, out, N);
}